// Round 1
// baseline (210.017 us; speedup 1.0000x reference)
//
#include <hip/hip_runtime.h>
#include <hip/hip_bf16.h>

typedef short short8 __attribute__((ext_vector_type(8)));
typedef float floatx4 __attribute__((ext_vector_type(4)));
typedef unsigned int uintx4 __attribute__((ext_vector_type(4)));
typedef unsigned int uintx2 __attribute__((ext_vector_type(2)));

__device__ __forceinline__ unsigned short f2bf_u(float f) {
    __hip_bfloat16 h = __float2bfloat16(f);   // RNE
    return *reinterpret_cast<unsigned short*>(&h);
}

// bf16 pair packed in a dword -> two fp32 values
__device__ __forceinline__ float bflo(unsigned u) {
    unsigned l = u << 16;
    return __builtin_bit_cast(float, l);
}
__device__ __forceinline__ float bfhi(unsigned u) {
    unsigned h = u & 0xffff0000u;
    return __builtin_bit_cast(float, h);
}
// uintx4 = 8 bf16 features -> accA (features 0..3), accB (features 4..7)
__device__ __forceinline__ void acc_u4(floatx4& A, floatx4& B, uintx4 u) {
    A.x += bflo(u.x); A.y += bfhi(u.x);
    A.z += bflo(u.y); A.w += bfhi(u.y);
    B.x += bflo(u.z); B.y += bfhi(u.z);
    B.z += bflo(u.w); B.w += bfhi(u.w);
}

// Kernel 1: W [128x128] fp32 row-major -> Wt [n][k] bf16 (transposed) so the
// MFMA A-fragment (8 consecutive k for fixed n) is one contiguous 16B load.
__global__ void wprep_kernel(const float* __restrict__ W,
                             __hip_bfloat16* __restrict__ Wt) {
    int tid = blockIdx.x * blockDim.x + threadIdx.x;   // 0..16383
    int n = tid & 127;
    int k = tid >> 7;
    Wt[n * 128 + k] = __float2bfloat16(W[k * 128 + n]);
}

// Kernel 2: Y = X @ W, bf16 out. 32 rows/block, 256 threads (4 waves).
// X staged fp32->bf16 into XOR-swizzled LDS (2-way max on b128 reads = free).
// MFMA swapped operands (A=Wt, B=X): lane's C-frag = 4 consecutive cols.
__global__ __launch_bounds__(256)
void gemm_kernel(const float* __restrict__ X,
                 const __hip_bfloat16* __restrict__ Wt,
                 char* __restrict__ Yb) {
    __shared__ unsigned short As[32 * 128];   // 8 KB, XOR-swizzled

    int tid = threadIdx.x;
    size_t rowbase = (size_t)blockIdx.x * 32;

    {
        int rr = tid >> 5;          // 0..7
        int c4 = (tid & 31) * 4;    // 0..124
        int kb = c4 >> 3;
        int ko = c4 & 7;
#pragma unroll
        for (int it = 0; it < 4; ++it) {
            int row = it * 8 + rr;
            // nontemporal: X is read exactly once; don't evict Yb from L2
            floatx4 f = __builtin_nontemporal_load(
                (const floatx4*)(X + (rowbase + row) * 128 + c4));
            uintx2 p;
            p.x = (unsigned)f2bf_u(f.x) | ((unsigned)f2bf_u(f.y) << 16);
            p.y = (unsigned)f2bf_u(f.z) | ((unsigned)f2bf_u(f.w) << 16);
            *(uintx2*)(As + row * 128 + ((kb ^ (row & 15)) << 3) + ko) = p;
        }
    }
    __syncthreads();

    int wv   = tid >> 6;
    int lane = tid & 63;
    int m16  = lane & 15;
    int quad = lane >> 4;
    int rt   = wv & 1;          // row-tile (16 rows)
    int ctb  = (wv >> 1) * 4;   // col-tile base

    floatx4 acc[4] = {{0,0,0,0},{0,0,0,0},{0,0,0,0},{0,0,0,0}};
    int arow = rt * 16 + m16;
#pragma unroll
    for (int s = 0; s < 4; ++s) {
        int kb = quad + s * 4;
        short8 bfrag = *(const short8*)(As + arow * 128 + ((kb ^ m16) << 3));
#pragma unroll
        for (int t = 0; t < 4; ++t) {
            short8 afrag = *(const short8*)(Wt + ((ctb + t) * 16 + m16) * 128 +
                                            quad * 8 + s * 32);
            acc[t] = __builtin_amdgcn_mfma_f32_16x16x32_bf16(afrag, bfrag,
                                                             acc[t], 0, 0, 0);
        }
    }

    size_t orow = rowbase + rt * 16 + m16;
#pragma unroll
    for (int t = 0; t < 4; ++t) {
        int ocol = (ctb + t) * 16 + quad * 4;
        uintx2 p;
        p.x = (unsigned)f2bf_u(acc[t][0]) | ((unsigned)f2bf_u(acc[t][1]) << 16);
        p.y = (unsigned)f2bf_u(acc[t][2]) | ((unsigned)f2bf_u(acc[t][3]) << 16);
        *(uintx2*)(Yb + orow * 256 + ocol * 2) = p;
    }
}

// Kernel 3: out[r,:] = sum_{e in row r} Yb[col[e],:]  (fp32 accumulate).
// v2 structure: 16 rows/block, one 16-lane group per row (no cross-slot
// reduce, full-wave stores). The block's whole contiguous edge range
// [rp[R], rp[R+16]) of column_index is staged into LDS once (coalesced),
// so inner-loop column reads are LDS broadcasts, not global loads.
// Main loop keeps 8 independent gathers in flight per lane; tail is a
// fully parallel masked pass (no serial tail).
__global__ __launch_bounds__(256)
void agg_kernel(const char* __restrict__ Yb,
                const int* __restrict__ row_pointers,
                const int* __restrict__ column_index,
                float* __restrict__ out) {
    constexpr int CAP = 2048;           // mean block edges = 256; 2048 = ample
    __shared__ int colS[CAP];
    __shared__ int rpS[17];

    int tid = threadIdx.x;
    int R = blockIdx.x * 16;
    if (tid < 17) rpS[tid] = row_pointers[R + tid];
    __syncthreads();

    int eblk0 = rpS[0];
    int cnt = rpS[16] - eblk0;
    int stage = cnt < CAP ? cnt : CAP;
    for (int i = tid; i < stage; i += 256)
        colS[i] = column_index[eblk0 + i];
    __syncthreads();

    int g  = tid >> 4;          // row group 0..15
    int l  = tid & 15;
    int fo = l * 16;            // byte offset within 256B bf16 row
    int r  = R + g;
    int e0 = rpS[g];
    int e1 = rpS[g + 1];

    floatx4 accA = {0.f, 0.f, 0.f, 0.f};
    floatx4 accB = {0.f, 0.f, 0.f, 0.f};

    if (e1 - eblk0 <= CAP) {
        int i = e0;
        int end8 = e0 + ((e1 - e0) & ~7);
        for (; i < end8; i += 8) {
            int k = i - eblk0;
            int c0 = colS[k + 0], c1 = colS[k + 1];
            int c2 = colS[k + 2], c3 = colS[k + 3];
            int c4 = colS[k + 4], c5 = colS[k + 5];
            int c6 = colS[k + 6], c7 = colS[k + 7];
            uintx4 u0 = *(const uintx4*)(Yb + (size_t)c0 * 256 + fo);
            uintx4 u1 = *(const uintx4*)(Yb + (size_t)c1 * 256 + fo);
            uintx4 u2 = *(const uintx4*)(Yb + (size_t)c2 * 256 + fo);
            uintx4 u3 = *(const uintx4*)(Yb + (size_t)c3 * 256 + fo);
            uintx4 u4 = *(const uintx4*)(Yb + (size_t)c4 * 256 + fo);
            uintx4 u5 = *(const uintx4*)(Yb + (size_t)c5 * 256 + fo);
            uintx4 u6 = *(const uintx4*)(Yb + (size_t)c6 * 256 + fo);
            uintx4 u7 = *(const uintx4*)(Yb + (size_t)c7 * 256 + fo);
            acc_u4(accA, accB, u0);
            acc_u4(accA, accB, u1);
            acc_u4(accA, accB, u2);
            acc_u4(accA, accB, u3);
            acc_u4(accA, accB, u4);
            acc_u4(accA, accB, u5);
            acc_u4(accA, accB, u6);
            acc_u4(accA, accB, u7);
        }
        // parallel masked tail: up to 7 edges, all loads independent
#pragma unroll
        for (int j = 0; j < 7; ++j) {
            int idx = i + j;
            if (idx < e1) {
                int c = colS[idx - eblk0];
                uintx4 u = *(const uintx4*)(Yb + (size_t)c * 256 + fo);
                acc_u4(accA, accB, u);
            }
        }
    } else {
        // safety fallback (block edge count > CAP): direct global reads
        for (int i = e0; i < e1; i += 4) {
#pragma unroll
            for (int j = 0; j < 4; ++j) {
                int idx = i + j;
                if (idx < e1) {
                    int c = column_index[idx];
                    uintx4 u = *(const uintx4*)(Yb + (size_t)c * 256 + fo);
                    acc_u4(accA, accB, u);
                }
            }
        }
    }

    float* dst = out + (size_t)r * 128 + l * 8;
    __builtin_nontemporal_store(accA, (floatx4*)dst);
    __builtin_nontemporal_store(accB, (floatx4*)(dst + 4));
}

extern "C" void kernel_launch(void* const* d_in, const int* in_sizes, int n_in,
                              void* d_out, int out_size, void* d_ws, size_t ws_size,
                              hipStream_t stream) {
    const float* X       = (const float*)d_in[0];   // [N, 128] fp32
    const float* W       = (const float*)d_in[1];   // [128, 128] fp32
    const int* row_ptrs  = (const int*)d_in[2];     // [N+1]
    const int* col_index = (const int*)d_in[3];     // [E]

    float* out = (float*)d_out;
    const int N = in_sizes[2] - 1;                  // 100000

    char* ws = (char*)d_ws;
    __hip_bfloat16* Wt = (__hip_bfloat16*)ws;       // 32 KB
    char* Yb = ws + 32768;                          // N*128 bf16 = 25.6 MB

    wprep_kernel<<<64, 256, 0, stream>>>(W, Wt);
    gemm_kernel<<<N / 32, 256, 0, stream>>>(X, Wt, Yb);           // N=3125*32
    agg_kernel<<<N / 16, 256, 0, stream>>>(Yb, row_ptrs, col_index, out);
}

// Round 2
// 208.759 us; speedup vs baseline: 1.0060x; 1.0060x over previous
//
#include <hip/hip_runtime.h>
#include <hip/hip_bf16.h>

typedef short short8 __attribute__((ext_vector_type(8)));
typedef float floatx4 __attribute__((ext_vector_type(4)));
typedef unsigned int uintx4 __attribute__((ext_vector_type(4)));
typedef unsigned int uintx2 __attribute__((ext_vector_type(2)));

__device__ __forceinline__ unsigned short f2bf_u(float f) {
    __hip_bfloat16 h = __float2bfloat16(f);   // RNE
    return *reinterpret_cast<unsigned short*>(&h);
}

// bf16 pair packed in a dword -> two fp32 values
__device__ __forceinline__ float bflo(unsigned u) {
    unsigned l = u << 16;
    return __builtin_bit_cast(float, l);
}
__device__ __forceinline__ float bfhi(unsigned u) {
    unsigned h = u & 0xffff0000u;
    return __builtin_bit_cast(float, h);
}
// uintx4 = 8 bf16 features -> accA (features 0..3), accB (features 4..7)
__device__ __forceinline__ void acc_u4(floatx4& A, floatx4& B, uintx4 u) {
    A.x += bflo(u.x); A.y += bfhi(u.x);
    A.z += bflo(u.y); A.w += bfhi(u.y);
    B.x += bflo(u.z); B.y += bfhi(u.z);
    B.z += bflo(u.w); B.w += bfhi(u.w);
}

// Kernel 1: W [128x128] fp32 row-major -> Wt [n][k] bf16 (transposed) so the
// MFMA A-fragment (8 consecutive k for fixed n) is one contiguous 16B load.
__global__ void wprep_kernel(const float* __restrict__ W,
                             __hip_bfloat16* __restrict__ Wt) {
    int tid = blockIdx.x * blockDim.x + threadIdx.x;   // 0..16383
    int n = tid & 127;
    int k = tid >> 7;
    Wt[n * 128 + k] = __float2bfloat16(W[k * 128 + n]);
}

// Kernel 2: Y = X @ W, bf16 out. 32 rows/block, 256 threads (4 waves).
// X staged fp32->bf16 into XOR-swizzled LDS (2-way max on b128 reads = free).
// MFMA swapped operands (A=Wt, B=X): lane's C-frag = 4 consecutive cols.
__global__ __launch_bounds__(256)
void gemm_kernel(const float* __restrict__ X,
                 const __hip_bfloat16* __restrict__ Wt,
                 char* __restrict__ Yb) {
    __shared__ unsigned short As[32 * 128];   // 8 KB, XOR-swizzled

    int tid = threadIdx.x;
    size_t rowbase = (size_t)blockIdx.x * 32;

    {
        int rr = tid >> 5;          // 0..7
        int c4 = (tid & 31) * 4;    // 0..124
        int kb = c4 >> 3;
        int ko = c4 & 7;
#pragma unroll
        for (int it = 0; it < 4; ++it) {
            int row = it * 8 + rr;
            // nontemporal: X is read exactly once; don't evict Yb from L2
            floatx4 f = __builtin_nontemporal_load(
                (const floatx4*)(X + (rowbase + row) * 128 + c4));
            uintx2 p;
            p.x = (unsigned)f2bf_u(f.x) | ((unsigned)f2bf_u(f.y) << 16);
            p.y = (unsigned)f2bf_u(f.z) | ((unsigned)f2bf_u(f.w) << 16);
            *(uintx2*)(As + row * 128 + ((kb ^ (row & 15)) << 3) + ko) = p;
        }
    }
    __syncthreads();

    int wv   = tid >> 6;
    int lane = tid & 63;
    int m16  = lane & 15;
    int quad = lane >> 4;
    int rt   = wv & 1;          // row-tile (16 rows)
    int ctb  = (wv >> 1) * 4;   // col-tile base

    floatx4 acc[4] = {{0,0,0,0},{0,0,0,0},{0,0,0,0},{0,0,0,0}};
    int arow = rt * 16 + m16;
#pragma unroll
    for (int s = 0; s < 4; ++s) {
        int kb = quad + s * 4;
        short8 bfrag = *(const short8*)(As + arow * 128 + ((kb ^ m16) << 3));
#pragma unroll
        for (int t = 0; t < 4; ++t) {
            short8 afrag = *(const short8*)(Wt + ((ctb + t) * 16 + m16) * 128 +
                                            quad * 8 + s * 32);
            acc[t] = __builtin_amdgcn_mfma_f32_16x16x32_bf16(afrag, bfrag,
                                                             acc[t], 0, 0, 0);
        }
    }

    size_t orow = rowbase + rt * 16 + m16;
#pragma unroll
    for (int t = 0; t < 4; ++t) {
        int ocol = (ctb + t) * 16 + quad * 4;
        uintx2 p;
        p.x = (unsigned)f2bf_u(acc[t][0]) | ((unsigned)f2bf_u(acc[t][1]) << 16);
        p.y = (unsigned)f2bf_u(acc[t][2]) | ((unsigned)f2bf_u(acc[t][3]) << 16);
        *(uintx2*)(Yb + orow * 256 + ocol * 2) = p;
    }
}

// Kernel 3: out[r,:] = sum_{e in row r} Yb[col[e],:]  (fp32 accumulate).
// v3: 16 rows/block, one 16-lane group per row. Single barrier: the colS
// staging bounds come from uniform scalar loads of row_pointers (not the
// rpS LDS round-trip). Inner loop software-pipelines the LDS column reads
// one iteration ahead so the 8 in-flight gathers issue immediately.
__global__ __launch_bounds__(256)
void agg_kernel(const char* __restrict__ Yb,
                const int* __restrict__ row_pointers,
                const int* __restrict__ column_index,
                float* __restrict__ out) {
    constexpr int CAP = 1024;           // mean block edges = 256 (Poisson);
    __shared__ int colS[CAP];           // >1024 essentially impossible,
    __shared__ int rpS[17];             // fallback path covers it anyway

    int tid = threadIdx.x;
    int R = blockIdx.x * 16;
    // uniform (SGPR) loads: staging bounds without a barrier dependency
    int rp0 = row_pointers[R];
    int cnt = row_pointers[R + 16] - rp0;
    if (tid < 17) rpS[tid] = row_pointers[R + tid];
    int stage = cnt < CAP ? cnt : CAP;
    for (int i = tid; i < stage; i += 256)
        colS[i] = column_index[rp0 + i];
    __syncthreads();

    int g  = tid >> 4;          // row group 0..15
    int l  = tid & 15;
    int fo = l * 16;            // byte offset within 256B row
    int r  = R + g;
    int e0 = rpS[g];
    int e1 = rpS[g + 1];

    floatx4 accA = {0.f, 0.f, 0.f, 0.f};
    floatx4 accB = {0.f, 0.f, 0.f, 0.f};

    if (cnt <= CAP) {
        int i = e0;
        int end8 = e0 + ((e1 - e0) & ~7);
        int c0, c1, c2, c3, c4, c5, c6, c7;
        if (i < end8) {
            int k = i - rp0;
            c0 = colS[k + 0]; c1 = colS[k + 1];
            c2 = colS[k + 2]; c3 = colS[k + 3];
            c4 = colS[k + 4]; c5 = colS[k + 5];
            c6 = colS[k + 6]; c7 = colS[k + 7];
        }
        while (i < end8) {
            uintx4 u0 = *(const uintx4*)(Yb + (size_t)c0 * 256 + fo);
            uintx4 u1 = *(const uintx4*)(Yb + (size_t)c1 * 256 + fo);
            uintx4 u2 = *(const uintx4*)(Yb + (size_t)c2 * 256 + fo);
            uintx4 u3 = *(const uintx4*)(Yb + (size_t)c3 * 256 + fo);
            uintx4 u4 = *(const uintx4*)(Yb + (size_t)c4 * 256 + fo);
            uintx4 u5 = *(const uintx4*)(Yb + (size_t)c5 * 256 + fo);
            uintx4 u6 = *(const uintx4*)(Yb + (size_t)c6 * 256 + fo);
            uintx4 u7 = *(const uintx4*)(Yb + (size_t)c7 * 256 + fo);
            i += 8;
            if (i < end8) {       // prefetch next iteration's columns
                int k = i - rp0;
                c0 = colS[k + 0]; c1 = colS[k + 1];
                c2 = colS[k + 2]; c3 = colS[k + 3];
                c4 = colS[k + 4]; c5 = colS[k + 5];
                c6 = colS[k + 6]; c7 = colS[k + 7];
            }
            acc_u4(accA, accB, u0);
            acc_u4(accA, accB, u1);
            acc_u4(accA, accB, u2);
            acc_u4(accA, accB, u3);
            acc_u4(accA, accB, u4);
            acc_u4(accA, accB, u5);
            acc_u4(accA, accB, u6);
            acc_u4(accA, accB, u7);
        }
        // parallel masked tail: up to 7 edges, all loads independent
#pragma unroll
        for (int j = 0; j < 7; ++j) {
            int idx = i + j;
            if (idx < e1) {
                int c = colS[idx - rp0];
                uintx4 u = *(const uintx4*)(Yb + (size_t)c * 256 + fo);
                acc_u4(accA, accB, u);
            }
        }
    } else {
        // safety fallback (block edge count > CAP): direct global reads
        for (int i = e0; i < e1; i += 4) {
#pragma unroll
            for (int j = 0; j < 4; ++j) {
                int idx = i + j;
                if (idx < e1) {
                    int c = column_index[idx];
                    uintx4 u = *(const uintx4*)(Yb + (size_t)c * 256 + fo);
                    acc_u4(accA, accB, u);
                }
            }
        }
    }

    float* dst = out + (size_t)r * 128 + l * 8;
    __builtin_nontemporal_store(accA, (floatx4*)dst);
    __builtin_nontemporal_store(accB, (floatx4*)(dst + 4));
}

extern "C" void kernel_launch(void* const* d_in, const int* in_sizes, int n_in,
                              void* d_out, int out_size, void* d_ws, size_t ws_size,
                              hipStream_t stream) {
    const float* X       = (const float*)d_in[0];   // [N, 128] fp32
    const float* W       = (const float*)d_in[1];   // [128, 128] fp32
    const int* row_ptrs  = (const int*)d_in[2];     // [N+1]
    const int* col_index = (const int*)d_in[3];     // [E]

    float* out = (float*)d_out;
    const int N = in_sizes[2] - 1;                  // 100000

    char* ws = (char*)d_ws;
    __hip_bfloat16* Wt = (__hip_bfloat16*)ws;       // 32 KB
    char* Yb = ws + 32768;                          // N*128 bf16 = 25.6 MB

    wprep_kernel<<<64, 256, 0, stream>>>(W, Wt);
    gemm_kernel<<<N / 32, 256, 0, stream>>>(X, Wt, Yb);           // N=3125*32
    agg_kernel<<<N / 16, 256, 0, stream>>>(Yb, row_ptrs, col_index, out);
}